// Round 6
// baseline (351.092 us; speedup 1.0000x reference)
//
#include <hip/hip_runtime.h>

// Problem constants (fixed by reference setup_inputs)
#define NB 8
#define NA 3
#define NH 160
#define NW 160
#define NCLS 80
#define NGT 32
#define NPB (NA * NH * NW)        // 76,800 cells per batch
#define TOTAL (NB * NPB)          // 614,400 cells
// Output: ONE flat float32 buffer, outputs concatenated in return order:
// p_bbox [8,76800,4] | cls_idx [8,76800] | score [8,76800] | loss [1]
#define OFF_CLSIDX (TOTAL * 4)    // 2,457,600  (f32 elements)
#define OFF_SCORE  (TOTAL * 5)    // 3,072,000
#define OFF_LOSS   (TOTAL * 6)    // 3,686,400

// Loss accumulator owned by this .so — no dependence on d_ws.
__device__ float g_acc;

__device__ __forceinline__ float det_sigmoid(float x) { return 1.0f / (1.0f + expf(-x)); }
__device__ __forceinline__ float det_bce(float x, float t) {
    return fmaxf(x, 0.0f) - x * t + log1pf(expf(-fabsf(x)));
}
// Anchor lookup for the 3 per-level anchors, via immediates.
__device__ __forceinline__ float det_aw3(int a) { return a == 0 ? 10.0f : (a == 1 ? 16.0f : 33.0f); }
__device__ __forceinline__ float det_ah3(int a) { return a == 0 ? 13.0f : (a == 1 ? 30.0f : 23.0f); }

// gt_mask layout detection (u8 bool vs int32), deterministic each call.
__device__ __forceinline__ bool det_mask_is_u8(const void* p) {
    const unsigned int* w = (const unsigned int*)p;
    unsigned int acc = 0;
#pragma unroll
    for (int k = 0; k < 64; k++) acc |= (w[k] & 0xFFFFFF00u);
    return acc != 0;
}
__device__ __forceinline__ bool det_mask_at(const void* p, bool u8mode, int idx) {
    return u8mode ? (((const unsigned char*)p)[idx] != 0)
                  : (((const int*)p)[idx] != 0);
}

// ---------------- Kernel 0: zero the accumulator ---------------------------
__global__ void det_zero_k() { g_acc = 0.0f; }

// ---------------- Kernel 1: per-gt losses (xy, wh, cls) --------------------
// One block of 256 threads = nB*G ground truths.
__global__ void det_gt_k(const float* __restrict__ t_bbox,
                         const float* __restrict__ cls_logits,
                         const float* __restrict__ gt_bboxes,
                         const int* __restrict__ gt_cls,
                         const void* __restrict__ gt_mask) {
    __shared__ int s_u8;
    if (threadIdx.x == 0) s_u8 = det_mask_is_u8(gt_mask) ? 1 : 0;
    __syncthreads();
    bool u8mode = (s_u8 != 0);

    int t = threadIdx.x;            // 0..255
    int b = t >> 5;
    int g = t & 31;
    float4 gtb = ((const float4*)gt_bboxes)[b * NGT + g];
    float cx = gtb.x, cy = gtb.y, gw = gtb.z, gh = gtb.w;

    const float aw9[9] = {10.f,16.f,33.f,30.f,62.f,59.f,116.f,156.f,373.f};
    const float ah9[9] = {13.f,30.f,23.f,61.f,45.f,119.f,90.f,198.f,326.f};
    float garea = gw * gh;
    int aidx = 0;
    float best = -1.0f;
#pragma unroll
    for (int k = 0; k < 9; k++) {
        float inter = fminf(gw, aw9[k]) * fminf(gh, ah9[k]);
        float uni = garea + aw9[k] * ah9[k] - inter;
        float r = inter / (uni + 1e-16f);
        if (r > best) { best = r; aidx = k; }
    }
    bool valid = det_mask_at(gt_mask, u8mode, b * NGT + g) && (aidx < NA);
    int ta = aidx % NA;
    int ti = min(max((int)(cx * 0.125f), 0), NW - 1);
    int tj = min(max((int)(cy * 0.125f), 0), NH - 1);
    size_t cell = ((size_t)(b * NA + ta) * NH + tj) * NW + ti;

    float4 tb = ((const float4*)t_bbox)[cell];
    float fx = cx * 0.125f; fx -= floorf(fx);
    float fy = cy * 0.125f; fy -= floorf(fy);
    float tx = (fx + 0.5f) * 0.5f;
    float ty = (fy + 0.5f) * 0.5f;
    float tw = sqrtf(gw / det_aw3(ta)) * 0.5f;
    float th = sqrtf(gh / det_ah3(ta)) * 0.5f;

    float l = det_bce(tb.x, tx) + det_bce(tb.y, ty) +
              det_bce(tb.z, tw) + det_bce(tb.w, th);

    const float4* cl = (const float4*)(cls_logits + cell * NCLS);
    int tc = gt_cls[b * NGT + g];
    float lc = 0.0f;
#pragma unroll
    for (int c4 = 0; c4 < NCLS / 4; c4++) {
        float4 v = cl[c4];
        int c = c4 * 4;
        lc += det_bce(v.x, (c + 0 == tc) ? 1.0f : 0.0f);
        lc += det_bce(v.y, (c + 1 == tc) ? 1.0f : 0.0f);
        lc += det_bce(v.z, (c + 2 == tc) ? 1.0f : 0.0f);
        lc += det_bce(v.w, (c + 3 == tc) ? 1.0f : 0.0f);
    }
    l += lc * (1.0f / NCLS);
    if (valid) atomicAdd(&g_acc, l);
}

// ---------------- Kernel 2a: bbox decode + IoU + conf loss -----------------
// One thread per cell; all global accesses coalesced (float4 / scalar).
__global__ __launch_bounds__(256) void det_bbox_k(
    const float* __restrict__ t_bbox,
    const float* __restrict__ conf_logits,
    const float* __restrict__ gt_bboxes,
    const void* __restrict__ gt_mask,
    float* __restrict__ out) {
    __shared__ float s_x1[NGT], s_y1[NGT], s_x2[NGT], s_y2[NGT], s_ar[NGT];
    __shared__ float s_m[NGT];
    __shared__ float s_part[4];
    __shared__ int s_u8;

    int gid = blockIdx.x * 256 + threadIdx.x;
    int b = gid / NPB;          // uniform within a block (NPB % 256 == 0)
    int r = gid % NPB;

    if (threadIdx.x == 0) s_u8 = det_mask_is_u8(gt_mask) ? 1 : 0;
    __syncthreads();
    if (threadIdx.x < NGT) {
        int g = threadIdx.x;
        float4 gtb = ((const float4*)gt_bboxes)[b * NGT + g];
        s_x1[g] = gtb.x - gtb.z * 0.5f;
        s_x2[g] = gtb.x + gtb.z * 0.5f;
        s_y1[g] = gtb.y - gtb.w * 0.5f;
        s_y2[g] = gtb.y + gtb.w * 0.5f;
        s_ar[g] = gtb.z * gtb.w;
        s_m[g]  = det_mask_at(gt_mask, s_u8 != 0, b * NGT + g) ? 1.0f : 0.0f;
    }
    __syncthreads();

    int a   = r / (NH * NW);
    int rem = r % (NH * NW);
    int j   = rem / NW;
    int i   = rem % NW;

    float4 tb = ((const float4*)t_bbox)[gid];
    float s0 = det_sigmoid(tb.x), s1 = det_sigmoid(tb.y);
    float s2 = det_sigmoid(tb.z), s3 = det_sigmoid(tb.w);
    float px = (s0 * 2.0f - 0.5f + (float)i) * 8.0f;
    float py = (s1 * 2.0f - 0.5f + (float)j) * 8.0f;
    float sw = s2 * 2.0f, sh = s3 * 2.0f;
    float pw = sw * sw * det_aw3(a);
    float ph = sh * sh * det_ah3(a);
    float4 pb; pb.x = px; pb.y = py; pb.z = pw; pb.w = ph;
    ((float4*)out)[gid] = pb;    // p_bbox f32 elements [4*gid, 4*gid+4)

    // max IoU vs masked gts (IoU >= 0: 0-init == ref's where/-1/has_gt chain)
    float px1 = px - pw * 0.5f, px2 = px + pw * 0.5f;
    float py1 = py - ph * 0.5f, py2 = py + ph * 0.5f;
    float parea = pw * ph;
    float maxiou = 0.0f;
#pragma unroll
    for (int g = 0; g < NGT; g++) {
        float iw = fmaxf(fminf(px2, s_x2[g]) - fmaxf(px1, s_x1[g]), 0.0f);
        float ih = fmaxf(fminf(py2, s_y2[g]) - fmaxf(py1, s_y1[g]), 0.0f);
        float inter = iw * ih;
        float uni = parea + s_ar[g] - inter;
        float iou = inter / (uni + 1e-16f);
        maxiou = fmaxf(maxiou, (s_m[g] != 0.0f) ? iou : 0.0f);
    }

    float lconf = det_bce(conf_logits[gid], maxiou);
#pragma unroll
    for (int off = 32; off > 0; off >>= 1) lconf += __shfl_down(lconf, off, 64);
    int wid = threadIdx.x >> 6, lane = threadIdx.x & 63;
    if (lane == 0) s_part[wid] = lconf;
    __syncthreads();
    if (threadIdx.x == 0)
        atomicAdd(&g_acc, s_part[0] + s_part[1] + s_part[2] + s_part[3]);
}

// ---------------- Kernel 2b: class argmax + score (quad-cooperative) -------
// 4 lanes per cell: lane q scans float4 chunks {q, q+4, ..., q+16} so each
// load instruction covers contiguous 64 B per quad (near-coalesced), then a
// 2-step __shfl_xor reduction with exact first-max tie-breaking.
__global__ __launch_bounds__(256) void det_cls_k(
    const float* __restrict__ conf_logits,
    const float* __restrict__ cls_logits,
    float* __restrict__ out) {
    int t = blockIdx.x * 256 + threadIdx.x;   // 0 .. TOTAL*4 - 1
    int cell = t >> 2;
    int q = t & 3;
    const float4* cl = (const float4*)(cls_logits + (size_t)cell * NCLS);
    float mx = -1e30f;
    int mi = 0;
#pragma unroll
    for (int k = 0; k < 5; k++) {
        int c4 = q + (k << 2);       // class chunks in increasing order per lane
        float4 v = cl[c4];
        int c = c4 << 2;
        if (v.x > mx) { mx = v.x; mi = c + 0; }
        if (v.y > mx) { mx = v.y; mi = c + 1; }
        if (v.z > mx) { mx = v.z; mi = c + 2; }
        if (v.w > mx) { mx = v.w; mi = c + 3; }
    }
    // quad reduce: lexicographic max on (value, -index) == jnp.argmax first-max
#pragma unroll
    for (int s = 1; s < 4; s <<= 1) {
        float ov = __shfl_xor(mx, s, 64);
        int   oi = __shfl_xor(mi, s, 64);
        if (ov > mx || (ov == mx && oi < mi)) { mx = ov; mi = oi; }
    }
    if (q == 0) {
        float score = det_sigmoid(conf_logits[cell]) * det_sigmoid(mx);
        out[OFF_CLSIDX + cell] = (float)mi;
        out[OFF_SCORE  + cell] = score;
    }
}

// ---------------- Kernel 3: finalize loss ----------------------------------
__global__ void det_fin_k(float* __restrict__ out) {
    out[OFF_LOSS] = g_acc * (1.0f / NB);
}

extern "C" void kernel_launch(void* const* d_in, const int* in_sizes, int n_in,
                              void* d_out, int out_size, void* d_ws, size_t ws_size,
                              hipStream_t stream) {
    (void)in_sizes; (void)n_in; (void)out_size; (void)d_ws; (void)ws_size;
    const float* t_bbox      = (const float*)d_in[0];
    const float* conf_logits = (const float*)d_in[1];
    const float* cls_logits  = (const float*)d_in[2];
    const float* gt_bboxes   = (const float*)d_in[3];
    const int*   gt_cls      = (const int*)d_in[4];
    const void*  gt_mask     = (const void*)d_in[5];  // layout auto-detected
    float* out = (float*)d_out;                       // float32 per reference

    det_zero_k<<<1, 1, 0, stream>>>();
    det_gt_k<<<1, 256, 0, stream>>>(t_bbox, cls_logits, gt_bboxes, gt_cls, gt_mask);
    det_bbox_k<<<TOTAL / 256, 256, 0, stream>>>(t_bbox, conf_logits,
                                                gt_bboxes, gt_mask, out);
    det_cls_k<<<(TOTAL * 4) / 256, 256, 0, stream>>>(conf_logits, cls_logits, out);
    det_fin_k<<<1, 1, 0, stream>>>(out);
}

// Round 7
// 329.566 us; speedup vs baseline: 1.0653x; 1.0653x over previous
//
#include <hip/hip_runtime.h>

// Problem constants (fixed by reference setup_inputs)
#define NB 8
#define NA 3
#define NH 160
#define NW 160
#define NCLS 80
#define NGT 32
#define NPB (NA * NH * NW)        // 76,800 cells per batch
#define TOTAL (NB * NPB)          // 614,400 cells
// Output: ONE flat float32 buffer, outputs concatenated in return order:
// p_bbox [8,76800,4] | cls_idx [8,76800] | score [8,76800] | loss [1]
#define OFF_CLSIDX (TOTAL * 4)    // 2,457,600  (f32 elements)
#define OFF_SCORE  (TOTAL * 5)    // 3,072,000
#define OFF_LOSS   (TOTAL * 6)    // 3,686,400

#define F4_PER_ROW 20             // 80 classes = 20 float4 per cell
#define LDS_ROW_F4 21             // +1 f4 pad to spread LDS banks

// Loss accumulator owned by this .so — no dependence on d_ws.
__device__ float g_acc;

__device__ __forceinline__ float det_sigmoid(float x) { return 1.0f / (1.0f + expf(-x)); }
__device__ __forceinline__ float det_bce(float x, float t) {
    return fmaxf(x, 0.0f) - x * t + log1pf(expf(-fabsf(x)));
}
__device__ __forceinline__ float det_aw3(int a) { return a == 0 ? 10.0f : (a == 1 ? 16.0f : 33.0f); }
__device__ __forceinline__ float det_ah3(int a) { return a == 0 ? 13.0f : (a == 1 ? 30.0f : 23.0f); }

// gt_mask layout detection (u8 bool vs int32), deterministic each call.
__device__ __forceinline__ bool det_mask_is_u8(const void* p) {
    const unsigned int* w = (const unsigned int*)p;
    unsigned int acc = 0;
#pragma unroll
    for (int k = 0; k < 64; k++) acc |= (w[k] & 0xFFFFFF00u);
    return acc != 0;
}
__device__ __forceinline__ bool det_mask_at(const void* p, bool u8mode, int idx) {
    return u8mode ? (((const unsigned char*)p)[idx] != 0)
                  : (((const int*)p)[idx] != 0);
}

// ---------------- Kernel 0: zero the accumulator ---------------------------
__global__ void det_zero_k() { g_acc = 0.0f; }

// ---------------- Kernel 1: per-gt losses (xy, wh, cls) --------------------
__global__ void det_gt_k(const float* __restrict__ t_bbox,
                         const float* __restrict__ cls_logits,
                         const float* __restrict__ gt_bboxes,
                         const int* __restrict__ gt_cls,
                         const void* __restrict__ gt_mask) {
    __shared__ int s_u8;
    if (threadIdx.x == 0) s_u8 = det_mask_is_u8(gt_mask) ? 1 : 0;
    __syncthreads();
    bool u8mode = (s_u8 != 0);

    int t = threadIdx.x;            // 0..255
    int b = t >> 5;
    int g = t & 31;
    float4 gtb = ((const float4*)gt_bboxes)[b * NGT + g];
    float cx = gtb.x, cy = gtb.y, gw = gtb.z, gh = gtb.w;

    const float aw9[9] = {10.f,16.f,33.f,30.f,62.f,59.f,116.f,156.f,373.f};
    const float ah9[9] = {13.f,30.f,23.f,61.f,45.f,119.f,90.f,198.f,326.f};
    float garea = gw * gh;
    int aidx = 0;
    float best = -1.0f;
#pragma unroll
    for (int k = 0; k < 9; k++) {
        float inter = fminf(gw, aw9[k]) * fminf(gh, ah9[k]);
        float uni = garea + aw9[k] * ah9[k] - inter;
        float r = inter / (uni + 1e-16f);
        if (r > best) { best = r; aidx = k; }
    }
    bool valid = det_mask_at(gt_mask, u8mode, b * NGT + g) && (aidx < NA);
    int ta = aidx % NA;
    int ti = min(max((int)(cx * 0.125f), 0), NW - 1);
    int tj = min(max((int)(cy * 0.125f), 0), NH - 1);
    size_t cell = ((size_t)(b * NA + ta) * NH + tj) * NW + ti;

    float4 tb = ((const float4*)t_bbox)[cell];
    float fx = cx * 0.125f; fx -= floorf(fx);
    float fy = cy * 0.125f; fy -= floorf(fy);
    float tx = (fx + 0.5f) * 0.5f;
    float ty = (fy + 0.5f) * 0.5f;
    float tw = sqrtf(gw / det_aw3(ta)) * 0.5f;
    float th = sqrtf(gh / det_ah3(ta)) * 0.5f;

    float l = det_bce(tb.x, tx) + det_bce(tb.y, ty) +
              det_bce(tb.z, tw) + det_bce(tb.w, th);

    const float4* cl = (const float4*)(cls_logits + cell * NCLS);
    int tc = gt_cls[b * NGT + g];
    float lc = 0.0f;
#pragma unroll
    for (int c4 = 0; c4 < NCLS / 4; c4++) {
        float4 v = cl[c4];
        int c = c4 * 4;
        lc += det_bce(v.x, (c + 0 == tc) ? 1.0f : 0.0f);
        lc += det_bce(v.y, (c + 1 == tc) ? 1.0f : 0.0f);
        lc += det_bce(v.z, (c + 2 == tc) ? 1.0f : 0.0f);
        lc += det_bce(v.w, (c + 3 == tc) ? 1.0f : 0.0f);
    }
    l += lc * (1.0f / NCLS);
    if (valid) atomicAdd(&g_acc, l);
}

// ---------------- Kernel 2: fused main kernel ------------------------------
// Block = 256 threads (4 waves) = 256 cells; NPB % 256 == 0 so blocks never
// straddle batches. Phase 1: bbox decode + IoU + conf-BCE (all coalesced).
// Phase 2: class argmax via LDS-staged, perfectly-coalesced tile loads —
// each wave stages 16 rows (320 consecutive float4s) with 5 lane-contiguous
// dwordx4 loads, then 4 lanes/cell scan LDS and quad-reduce (first-max).
__global__ __launch_bounds__(256) void det_main_k(
    const float* __restrict__ t_bbox,
    const float* __restrict__ conf_logits,
    const float* __restrict__ cls_logits,
    const float* __restrict__ gt_bboxes,
    const void* __restrict__ gt_mask,
    float* __restrict__ out) {
    __shared__ float4 s_cls[4][16 * LDS_ROW_F4];   // 21.5 KB, per-wave tiles
    __shared__ float s_x1[NGT], s_y1[NGT], s_x2[NGT], s_y2[NGT], s_ar[NGT];
    __shared__ float s_m[NGT];
    __shared__ float s_part[4];
    __shared__ int s_u8;

    int tid = threadIdx.x;
    int blockCell = blockIdx.x * 256;
    int gid = blockCell + tid;
    int b = gid / NPB;          // uniform within a block
    int r = gid % NPB;

    if (tid == 0) s_u8 = det_mask_is_u8(gt_mask) ? 1 : 0;
    __syncthreads();
    if (tid < NGT) {
        int g = tid;
        float4 gtb = ((const float4*)gt_bboxes)[b * NGT + g];
        s_x1[g] = gtb.x - gtb.z * 0.5f;
        s_x2[g] = gtb.x + gtb.z * 0.5f;
        s_y1[g] = gtb.y - gtb.w * 0.5f;
        s_y2[g] = gtb.y + gtb.w * 0.5f;
        s_ar[g] = gtb.z * gtb.w;
        s_m[g]  = det_mask_at(gt_mask, s_u8 != 0, b * NGT + g) ? 1.0f : 0.0f;
    }
    __syncthreads();

    // ---- Phase 1: bbox decode + IoU + conf loss (thread t <-> cell gid) ----
    int a   = r / (NH * NW);
    int rem = r % (NH * NW);
    int j   = rem / NW;
    int i   = rem % NW;

    float4 tb = ((const float4*)t_bbox)[gid];
    float s0 = det_sigmoid(tb.x), s1 = det_sigmoid(tb.y);
    float s2 = det_sigmoid(tb.z), s3 = det_sigmoid(tb.w);
    float px = (s0 * 2.0f - 0.5f + (float)i) * 8.0f;
    float py = (s1 * 2.0f - 0.5f + (float)j) * 8.0f;
    float sw = s2 * 2.0f, sh = s3 * 2.0f;
    float pw = sw * sw * det_aw3(a);
    float ph = sh * sh * det_ah3(a);
    float4 pb; pb.x = px; pb.y = py; pb.z = pw; pb.w = ph;
    ((float4*)out)[gid] = pb;

    float px1 = px - pw * 0.5f, px2 = px + pw * 0.5f;
    float py1 = py - ph * 0.5f, py2 = py + ph * 0.5f;
    float parea = pw * ph;
    float maxiou = 0.0f;
#pragma unroll
    for (int g = 0; g < NGT; g++) {
        float iw = fmaxf(fminf(px2, s_x2[g]) - fmaxf(px1, s_x1[g]), 0.0f);
        float ih = fmaxf(fminf(py2, s_y2[g]) - fmaxf(py1, s_y1[g]), 0.0f);
        float inter = iw * ih;
        float uni = parea + s_ar[g] - inter;
        float iou = inter / (uni + 1e-16f);
        maxiou = fmaxf(maxiou, (s_m[g] != 0.0f) ? iou : 0.0f);
    }

    float confl = conf_logits[gid];
    float sconf = det_sigmoid(confl);          // kept for phase 2 via shuffle
    float lconf = det_bce(confl, maxiou);
#pragma unroll
    for (int off = 32; off > 0; off >>= 1) lconf += __shfl_down(lconf, off, 64);
    int w = tid >> 6, l = tid & 63;
    if (l == 0) s_part[w] = lconf;
    __syncthreads();
    if (tid == 0)
        atomicAdd(&g_acc, s_part[0] + s_part[1] + s_part[2] + s_part[3]);

    // ---- Phase 2: class argmax + score, LDS-staged coalesced ----
    int cl_ = l >> 2;            // local cell within 16-row tile
    int q   = l & 3;             // quad lane: scans cols [5q, 5q+5)
    const float4* g4 = (const float4*)cls_logits;
    int wbase = blockCell + w * 64;            // first cell of this wave

#pragma unroll
    for (int it = 0; it < 4; ++it) {
        int tileCell = wbase + it * 16;
        size_t f4base = (size_t)tileCell * F4_PER_ROW;
        __syncthreads();                       // LDS tile reuse guard
#pragma unroll
        for (int k = 0; k < 5; ++k) {          // 320 consecutive f4 per tile
            int f = k * 64 + l;
            float4 v = g4[f4base + f];
            int rr = f / F4_PER_ROW;
            int cc = f - rr * F4_PER_ROW;
            s_cls[w][rr * LDS_ROW_F4 + cc] = v;
        }
        __syncthreads();

        float mx = -1e30f;
        int mi = 0;
#pragma unroll
        for (int k = 0; k < 5; ++k) {
            int col = q * 5 + k;               // ascending within lane
            float4 v = s_cls[w][cl_ * LDS_ROW_F4 + col];
            int c = col * 4;
            if (v.x > mx) { mx = v.x; mi = c + 0; }
            if (v.y > mx) { mx = v.y; mi = c + 1; }
            if (v.z > mx) { mx = v.z; mi = c + 2; }
            if (v.w > mx) { mx = v.w; mi = c + 3; }
        }
        // quad reduce: lexicographic (value, lower index) == jnp first-max
#pragma unroll
        for (int s = 1; s < 4; s <<= 1) {
            float ov = __shfl_xor(mx, s, 64);
            int   oi = __shfl_xor(mi, s, 64);
            if (ov > mx || (ov == mx && oi < mi)) { mx = ov; mi = oi; }
        }
        // sigmoid(conf) of this tile's cell lives in lane it*16+cl_ (phase 1)
        float sc = __shfl(sconf, it * 16 + cl_, 64);
        if (q == 0) {
            int cellg = tileCell + cl_;
            out[OFF_CLSIDX + cellg] = (float)mi;
            out[OFF_SCORE  + cellg] = sc * det_sigmoid(mx);
        }
    }
}

// ---------------- Kernel 3: finalize loss ----------------------------------
__global__ void det_fin_k(float* __restrict__ out) {
    out[OFF_LOSS] = g_acc * (1.0f / NB);
}

extern "C" void kernel_launch(void* const* d_in, const int* in_sizes, int n_in,
                              void* d_out, int out_size, void* d_ws, size_t ws_size,
                              hipStream_t stream) {
    (void)in_sizes; (void)n_in; (void)out_size; (void)d_ws; (void)ws_size;
    const float* t_bbox      = (const float*)d_in[0];
    const float* conf_logits = (const float*)d_in[1];
    const float* cls_logits  = (const float*)d_in[2];
    const float* gt_bboxes   = (const float*)d_in[3];
    const int*   gt_cls      = (const int*)d_in[4];
    const void*  gt_mask     = (const void*)d_in[5];  // layout auto-detected
    float* out = (float*)d_out;                       // float32 per reference

    det_zero_k<<<1, 1, 0, stream>>>();
    det_gt_k<<<1, 256, 0, stream>>>(t_bbox, cls_logits, gt_bboxes, gt_cls, gt_mask);
    det_main_k<<<TOTAL / 256, 256, 0, stream>>>(t_bbox, conf_logits, cls_logits,
                                                gt_bboxes, gt_mask, out);
    det_fin_k<<<1, 1, 0, stream>>>(out);
}